// Round 8
// baseline (166.871 us; speedup 1.0000x reference)
//
#include <hip/hip_runtime.h>
#include <math.h>

#define NFFT   2048
#define N1     1024
#define K1     1025
#define KPAD   36
#define MTOT   1097   // K1 + 2*KPAD
#define NFRAMES 1001
#define TLEN   120000
#define BATCH  8
#define FPER   120
#define PIF 3.14159265358979323846f

// LDS swizzle for 8B (float2) elements; balanced for all radix-4 strides and
// the stride-16 brev gathers.
#define A(i) ((i) + ((i) >> 4))      // max 1023 -> 1086; array sized 1088

typedef float2 cpx;
__device__ __forceinline__ cpx cmul(cpx a, cpx b) {
    return make_float2(a.x * b.x - a.y * b.y, a.x * b.y + a.y * b.x);
}
__device__ __forceinline__ cpx cadd(cpx a, cpx b) { return make_float2(a.x + b.x, a.y + b.y); }
__device__ __forceinline__ cpx csub(cpx a, cpx b) { return make_float2(a.x - b.x, a.y - b.y); }

__device__ __forceinline__ int brev10(int v) {
    return (int)(__brev((unsigned)v) >> 22);
}

// ---- fused radix-4 DIF stage on TWO independent arrays per barrier ----
// Two frames share each barrier: halves barrier count per frame and doubles
// independent work (ILP) per inter-barrier region.
template<int H>
__device__ __forceinline__ void dif_stage2(cpx* cA, cpx* cB, int tid, cpx w1) {
    int r  = tid & (H / 2 - 1);
    int i0 = (tid / (H / 2)) * (2 * H) + r;
    int ia = A(i0), ib = A(i0 + H / 2), ic = A(i0 + H), id = A(i0 + 3 * H / 2);
    cpx w1n = make_float2(w1.y, -w1.x);                       // -i*w1
    cpx w2  = make_float2(w1.x * w1.x - w1.y * w1.y, 2.0f * w1.x * w1.y);
    cpx aA = cA[ia], bA = cA[ib], ccA = cA[ic], dA = cA[id];
    cpx aB = cB[ia], bB = cB[ib], ccB = cB[ic], dB = cB[id];
    {
        cpx a1 = cadd(aA, ccA);
        cpx c1 = cmul(csub(aA, ccA), w1);
        cpx b1 = cadd(bA, dA);
        cpx d1 = cmul(csub(bA, dA), w1n);
        cA[ia] = cadd(a1, b1);
        cA[ib] = cmul(csub(a1, b1), w2);
        cA[ic] = cadd(c1, d1);
        cA[id] = cmul(csub(c1, d1), w2);
    }
    {
        cpx a1 = cadd(aB, ccB);
        cpx c1 = cmul(csub(aB, ccB), w1);
        cpx b1 = cadd(bB, dB);
        cpx d1 = cmul(csub(bB, dB), w1n);
        cB[ia] = cadd(a1, b1);
        cB[ib] = cmul(csub(a1, b1), w2);
        cB[ic] = cadd(c1, d1);
        cB[id] = cmul(csub(c1, d1), w2);
    }
    __syncthreads();
}

__device__ __forceinline__ void dif_last2_2(cpx* cA, cpx* cB, int tid) {
    int i0 = 4 * tid;
    int ia = A(i0), ib = A(i0 + 1), ic = A(i0 + 2), id = A(i0 + 3);
    {
        cpx a = cA[ia], b = cA[ib], cc = cA[ic], d = cA[id];
        cpx a1 = cadd(a, cc);
        cpx c1 = csub(a, cc);
        cpx b1 = cadd(b, d);
        cpx bd = csub(b, d);
        cpx d1 = make_float2(bd.y, -bd.x);                    // -i*(b-d)
        cA[ia] = cadd(a1, b1);
        cA[ib] = csub(a1, b1);
        cA[ic] = cadd(c1, d1);
        cA[id] = csub(c1, d1);
    }
    {
        cpx a = cB[ia], b = cB[ib], cc = cB[ic], d = cB[id];
        cpx a1 = cadd(a, cc);
        cpx c1 = csub(a, cc);
        cpx b1 = cadd(b, d);
        cpx bd = csub(b, d);
        cpx d1 = make_float2(bd.y, -bd.x);
        cB[ia] = cadd(a1, b1);
        cB[ib] = csub(a1, b1);
        cB[ic] = cadd(c1, d1);
        cB[id] = csub(c1, d1);
    }
    __syncthreads();
}

__device__ __forceinline__ void fft1024_2(cpx* cA, cpx* cB, int tid, const cpx* tw) {
    dif_stage2<512>(cA, cB, tid, tw[0]);
    dif_stage2<128>(cA, cB, tid, tw[1]);
    dif_stage2<32>(cA, cB, tid, tw[2]);
    dif_stage2<8>(cA, cB, tid, tw[3]);
    dif_last2_2(cA, cB, tid);
}

// Unpack: X[k] = E + w*O, w = W_2048^k (precomputed by caller).
__device__ __forceinline__ cpx unpack_k(const cpx* s_c, int k, cpx w) {
    int kk = k & (N1 - 1);
    int mm = (N1 - kk) & (N1 - 1);
    cpx Zk = s_c[A(brev10(kk))];
    cpx Zm = s_c[A(brev10(mm))];
    float Ex = 0.5f * (Zk.x + Zm.x), Ey = 0.5f * (Zk.y - Zm.y);
    float Ox = 0.5f * (Zk.y + Zm.y), Oy = 0.5f * (Zm.x - Zk.x);
    return make_float2(Ex + w.x * Ox - w.y * Oy,
                       Ey + w.x * Oy + w.y * Ox);
}

// extraction + window + normalize + pack into s_c (natural order).
// One internal barrier; caller must barrier before FFT.
__device__ __forceinline__ void extract_pack(const float* __restrict__ xrow,
                                             int n, float f0, cpx* s_c,
                                             volatile float* scanseg,
                                             int tid, int lane, int wid) {
    float fr[8], wn[8];
    float hwl = rintf(36000.0f / f0);
    float s_w2 = 0.0f, s_w = 0.0f, s_fw = 0.0f;
    int base_idx = n * FPER - N1 + 8 * tid;
#pragma unroll
    for (int j = 0; j < 8; ++j) {
        int l = 8 * tid + j;
        float relf = (float)(l - N1);
        int idx = max(0, min(TLEN - 1, base_idx + j));
        fr[j] = xrow[idx];
        float w = 0.0f;
        if (fabsf(relf) <= hwl) {
            w = 0.5f * __cosf(PIF * relf / 36000.0f * f0) + 0.5f;
        }
        wn[j] = w;
        s_w2 += w * w;
        s_w  += w;
        s_fw += fr[j] * w;
    }
#pragma unroll
    for (int off = 32; off > 0; off >>= 1) {
        s_w2 += __shfl_down(s_w2, off, 64);
        s_w  += __shfl_down(s_w,  off, 64);
        s_fw += __shfl_down(s_fw, off, 64);
    }
    if (lane == 0) {
        scanseg[wid]     = s_w2;
        scanseg[4 + wid] = s_w;
        scanseg[8 + wid] = s_fw;
    }
    __syncthreads();
    float w2sum = scanseg[0] + scanseg[1] + scanseg[2] + scanseg[3];
    float wsum  = scanseg[4] + scanseg[5] + scanseg[6] + scanseg[7];
    float fwsum = scanseg[8] + scanseg[9] + scanseg[10] + scanseg[11];
    float wscale = 1.0f / sqrtf(w2sum);
    float dc = fwsum / wsum;
#pragma unroll
    for (int j = 0; j < 4; ++j) {
        float v0 = wscale * wn[2 * j]     * (fr[2 * j]     - dc);
        float v1 = wscale * wn[2 * j + 1] * (fr[2 * j + 1] - dc);
        s_c[A(4 * tid + j)] = make_float2(v0, v1);
    }
}

// NO min-waves arg (r6: (256,w) caps VGPR at 256/w -> spills for w>=5, and
// pins residency for small w). Spill canary: WRITE_SIZE must stay ~32.3 MB.
__global__ __launch_bounds__(256)
void cheaptrick_kernel(const float* __restrict__ x,
                       const float* __restrict__ f0in,
                       float* __restrict__ out) {
    __shared__ cpx   s_cA[1088];
    __shared__ cpx   s_cB[1088];
    __shared__ float s_PA[1026];
    __shared__ float s_PB[1026];
    __shared__ float s_scan[32];
    // s_C aliases s_c storage: scan writes happen after FFT1 data is dead
    // (>=2 barriers), s_C dead before FFT2 pack overwrites (barrier between).
    float* s_CA = (float*)s_cA;   // needs 1097 floats = 4388 B < 8704 B
    float* s_CB = (float*)s_cB;

    const int tid  = threadIdx.x;
    const int lane = tid & 63;
    const int wid  = tid >> 6;
    const int b    = blockIdx.y;
    const int nA   = 2 * blockIdx.x;
    const bool hasB = (nA + 1) < NFRAMES;
    const int nB   = hasB ? (nA + 1) : nA;

    const float F_MIN = 72000.0f / 2045.0f;
    float f0A = f0in[b * NFRAMES + nA];
    if (f0A <= F_MIN) f0A = 500.0f;
    float f0B = f0in[b * NFRAMES + nB];
    if (f0B <= F_MIN) f0B = 500.0f;

    const float* xrow = x + (size_t)b * TLEN;
    extract_pack(xrow, nA, f0A, s_cA, s_scan,      tid, lane, wid);
    extract_pack(xrow, nB, f0B, s_cB, s_scan + 16, tid, lane, wid);

    // ---- twiddle caches (computed once, reused by all 6 FFTs) ----
    cpx tw[4], u2048;
    {
        float sn, cs;
        __sincosf(-PIF * (float)(tid & 255) * (1.0f / 512.0f), &sn, &cs);
        tw[0] = make_float2(cs, sn);
        __sincosf(-PIF * (float)(tid & 63) * (1.0f / 128.0f), &sn, &cs);
        tw[1] = make_float2(cs, sn);
        __sincosf(-PIF * (float)(tid & 15) * (1.0f / 32.0f), &sn, &cs);
        tw[2] = make_float2(cs, sn);
        __sincosf(-PIF * (float)(tid & 3) * (1.0f / 8.0f), &sn, &cs);
        tw[3] = make_float2(cs, sn);
        __sincosf(-PIF * (float)tid * (1.0f / 1024.0f), &sn, &cs);
        u2048 = make_float2(cs, sn);          // W_2048^tid
    }
    const float RH = 0.70710678118654752f;
    const cpx W8[5] = { make_float2(1.0f, 0.0f), make_float2(RH, -RH),
                        make_float2(0.0f, -1.0f), make_float2(-RH, -RH),
                        make_float2(-1.0f, 0.0f) };           // W_2048^(256c)

    __syncthreads();
    fft1024_2(s_cA, s_cB, tid, tw);

    // ---- unpack + power spectrum (both frames) ----
#pragma unroll
    for (int c5 = 0; c5 < 5; ++c5) {
        int k = tid + (c5 << 8);
        if (k < K1) {
            cpx w = cmul(u2048, W8[c5]);
            cpx XA = unpack_k(s_cA, k, w);
            s_PA[k] = XA.x * XA.x + XA.y * XA.y;
            cpx XB = unpack_k(s_cB, k, w);
            s_PB[k] = XB.x * XB.x + XB.y * XB.y;
        }
    }
    __syncthreads();

    // ---- sub-f0 replacement (both frames share barriers) ----
    float rateA = f0A * (2048.0f / 24000.0f);
    float rateB = f0B * (2048.0f / 24000.0f);
    int kmaxA = (int)floorf(rateA);
    int kmaxB = (int)floorf(rateB);
    float replA = 0.0f, replB = 0.0f;
    if (tid <= kmaxA) {
        float m = rateA - (float)tid;
        int lo = (int)floorf(m);
        lo = max(0, min(K1 - 2, lo));
        float frac = m - (float)lo;
        replA = s_PA[lo] * (1.0f - frac) + s_PA[lo + 1] * frac;
    }
    if (tid <= kmaxB) {
        float m = rateB - (float)tid;
        int lo = (int)floorf(m);
        lo = max(0, min(K1 - 2, lo));
        float frac = m - (float)lo;
        replB = s_PB[lo] * (1.0f - frac) + s_PB[lo + 1] * frac;
    }
    __syncthreads();
    if (tid <= kmaxA) s_PA[tid] += replA;
    if (tid <= kmaxB) s_PB[tid] += replB;
    __syncthreads();

    // ---- reflected cumsum: serial-5 + dual wave shuffle scan ----
    float locA[5], locB[5];
    float runA = 0.0f, runB = 0.0f;
    int basej = tid * 5;
#pragma unroll
    for (int c = 0; c < 5; ++c) {
        int j = basej + c;
        float vA = 0.0f, vB = 0.0f;
        if (j < MTOT) {
            int a = abs(j - KPAD);
            if (a > N1) a = NFFT - a;
            vA = s_PA[a] * (24000.0f / 2048.0f);
            vB = s_PB[a] * (24000.0f / 2048.0f);
        }
        runA += vA; locA[c] = runA;
        runB += vB; locB[c] = runB;
    }
    float vA = runA, vB = runB;
#pragma unroll
    for (int off = 1; off < 64; off <<= 1) {
        float oA = __shfl_up(vA, off, 64);
        float oB = __shfl_up(vB, off, 64);
        if (lane >= off) { vA += oA; vB += oB; }
    }
    if (lane == 63) { s_scan[wid] = vA; s_scan[16 + wid] = vB; }
    __syncthreads();
    float wbA = 0.0f, wbB = 0.0f;
#pragma unroll
    for (int w = 0; w < 4; ++w) {
        if (w < wid) { wbA += s_scan[w]; wbB += s_scan[16 + w]; }
    }
    float prefA = wbA + vA - runA;
    float prefB = wbB + vB - runB;
#pragma unroll
    for (int c = 0; c < 5; ++c) {
        int j = basej + c;
        if (j < MTOT) { s_CA[j] = prefA + locA[c]; s_CB[j] = prefB + locB[c]; }
    }
    __syncthreads();

    // ---- rectangular smoothing + log (both frames) ----
    float widthA = f0A * (2.0f / 3.0f), wbinsA = widthA * (2048.0f / 24000.0f);
    float widthB = f0B * (2.0f / 3.0f), wbinsB = widthB * (2048.0f / 24000.0f);
#pragma unroll
    for (int c5 = 0; c5 < 5; ++c5) {
        int k = tid + (c5 << 8);
        if (k < K1) {
            {
                float pos_lo = (float)k - 0.5f * wbinsA + ((float)KPAD - 0.5f);
                float pos_hi = pos_lo + wbinsA;
                int llo = (int)floorf(pos_lo); llo = max(0, min(MTOT - 2, llo));
                float flo = pos_lo - (float)llo;
                float clo = s_CA[llo] + (s_CA[llo + 1] - s_CA[llo]) * flo;
                int lhi = (int)floorf(pos_hi); lhi = max(0, min(MTOT - 2, lhi));
                float fhi = pos_hi - (float)lhi;
                float chi = s_CA[lhi] + (s_CA[lhi + 1] - s_CA[lhi]) * fhi;
                s_PA[k] = __logf((chi - clo) / widthA);
            }
            {
                float pos_lo = (float)k - 0.5f * wbinsB + ((float)KPAD - 0.5f);
                float pos_hi = pos_lo + wbinsB;
                int llo = (int)floorf(pos_lo); llo = max(0, min(MTOT - 2, llo));
                float flo = pos_lo - (float)llo;
                float clo = s_CB[llo] + (s_CB[llo + 1] - s_CB[llo]) * flo;
                int lhi = (int)floorf(pos_hi); lhi = max(0, min(MTOT - 2, lhi));
                float fhi = pos_hi - (float)lhi;
                float chi = s_CB[lhi] + (s_CB[lhi + 1] - s_CB[lhi]) * fhi;
                s_PB[k] = __logf((chi - clo) / widthB);
            }
        }
    }
    __syncthreads();

    // ---- FFT2: pack even extensions of logP ----
#pragma unroll
    for (int c = 0; c < 4; ++c) {
        int m = tid + (c << 8);
        int j0 = 2 * m;
        int j1 = 2 * m + 1;
        float a0 = (j0 <= N1) ? s_PA[j0] : s_PA[NFFT - j0];
        float a1 = (j1 <= N1) ? s_PA[j1] : s_PA[NFFT - j1];
        s_cA[A(m)] = make_float2(a0, a1);
        float b0 = (j0 <= N1) ? s_PB[j0] : s_PB[NFFT - j0];
        float b1 = (j1 <= N1) ? s_PB[j1] : s_PB[NFFT - j1];
        s_cB[A(m)] = make_float2(b0, b1);
    }
    __syncthreads();
    fft1024_2(s_cA, s_cB, tid, tw);

    // ---- unpack + lifter -> s_P ; cl via cos(2a)=1-2sin^2(a) ----
#pragma unroll
    for (int c5 = 0; c5 < 5; ++c5) {
        int k = tid + (c5 << 8);
        if (k < K1) {
            cpx w = cmul(u2048, W8[c5]);
            {
                cpx X = unpack_k(s_cA, k, w);
                float cep = X.x * (1.0f / 2048.0f);
                float pz = PIF * f0A * ((float)k * (1.0f / 24000.0f));
                float s = __sinf(pz);
                float sl = (k != 0) ? (s / pz) : 1.0f;
                float cl = 1.0f + 0.6f * s * s;
                s_PA[k] = cep * sl * cl;
            }
            {
                cpx X = unpack_k(s_cB, k, w);
                float cep = X.x * (1.0f / 2048.0f);
                float pz = PIF * f0B * ((float)k * (1.0f / 24000.0f));
                float s = __sinf(pz);
                float sl = (k != 0) ? (s / pz) : 1.0f;
                float cl = 1.0f + 0.6f * s * s;
                s_PB[k] = cep * sl * cl;
            }
        }
    }
    __syncthreads();

    // ---- FFT3: pack even extensions of lifted cepstrum ----
#pragma unroll
    for (int c = 0; c < 4; ++c) {
        int m = tid + (c << 8);
        int j0 = 2 * m;
        int j1 = 2 * m + 1;
        float a0 = (j0 <= N1) ? s_PA[j0] : s_PA[NFFT - j0];
        float a1 = (j1 <= N1) ? s_PA[j1] : s_PA[NFFT - j1];
        s_cA[A(m)] = make_float2(a0, a1);
        float b0 = (j0 <= N1) ? s_PB[j0] : s_PB[NFFT - j0];
        float b1 = (j1 <= N1) ? s_PB[j1] : s_PB[NFFT - j1];
        s_cB[A(m)] = make_float2(b0, b1);
    }
    __syncthreads();
    fft1024_2(s_cA, s_cB, tid, tw);

    // ---- unpack + store ----
    float* orowA = out + (size_t)(b * NFRAMES + nA) * K1;
    float* orowB = out + (size_t)(b * NFRAMES + nB) * K1;
#pragma unroll
    for (int c5 = 0; c5 < 5; ++c5) {
        int k = tid + (c5 << 8);
        if (k < K1) {
            cpx w = cmul(u2048, W8[c5]);
            cpx XA = unpack_k(s_cA, k, w);
            orowA[k] = XA.x;
            if (hasB) {
                cpx XB = unpack_k(s_cB, k, w);
                orowB[k] = XB.x;
            }
        }
    }
}

extern "C" void kernel_launch(void* const* d_in, const int* in_sizes, int n_in,
                              void* d_out, int out_size, void* d_ws, size_t ws_size,
                              hipStream_t stream) {
    (void)in_sizes; (void)n_in; (void)d_ws; (void)ws_size; (void)out_size;
    const float* x  = (const float*)d_in[0];
    const float* f0 = (const float*)d_in[1];
    float* out = (float*)d_out;
    dim3 grid((NFRAMES + 1) / 2, BATCH);
    hipLaunchKernelGGL(cheaptrick_kernel, grid, dim3(256), 0, stream, x, f0, out);
}

// Round 9
// 150.802 us; speedup vs baseline: 1.1066x; 1.1066x over previous
//
#include <hip/hip_runtime.h>
#include <math.h>

#define NFFT   2048
#define N1     1024
#define K1     1025
#define KPAD   36
#define MTOT   1097   // K1 + 2*KPAD
#define NFRAMES 1001
#define TLEN   120000
#define BATCH  8
#define FPER   120
#define PIF 3.14159265358979323846f

// LDS swizzle for 8B (float2) elements; balanced for all radix-4 strides and
// the stride-16 brev gathers.
#define A(i) ((i) + ((i) >> 4))      // max 1023 -> 1086; array sized 1088

typedef float2 cpx;
__device__ __forceinline__ cpx cmul(cpx a, cpx b) {
    return make_float2(a.x * b.x - a.y * b.y, a.x * b.y + a.y * b.x);
}
__device__ __forceinline__ cpx cadd(cpx a, cpx b) { return make_float2(a.x + b.x, a.y + b.y); }
__device__ __forceinline__ cpx csub(cpx a, cpx b) { return make_float2(a.x - b.x, a.y - b.y); }

__device__ __forceinline__ int brev10(int v) {
    return (int)(__brev((unsigned)v) >> 22);
}

// ---- fused radix-4 DIF stage (spans H and H/2); w1 = W_{2H}^{tid&(H/2-1)} ----
template<int H>
__device__ __forceinline__ void dif_fused(cpx* c, int tid, cpx w1) {
    int r  = tid & (H / 2 - 1);
    int i0 = (tid / (H / 2)) * (2 * H) + r;
    int ia = A(i0), ib = A(i0 + H / 2), ic = A(i0 + H), id = A(i0 + 3 * H / 2);
    cpx a = c[ia], b = c[ib], cc = c[ic], d = c[id];
    cpx w1n = make_float2(w1.y, -w1.x);                       // -i*w1
    cpx w2  = make_float2(w1.x * w1.x - w1.y * w1.y, 2.0f * w1.x * w1.y);
    cpx a1 = cadd(a, cc);
    cpx c1 = cmul(csub(a, cc), w1);
    cpx b1 = cadd(b, d);
    cpx d1 = cmul(csub(b, d), w1n);
    c[ia] = cadd(a1, b1);
    c[ib] = cmul(csub(a1, b1), w2);
    c[ic] = cadd(c1, d1);
    c[id] = cmul(csub(c1, d1), w2);
    __syncthreads();
}

// last stage (H=2): twiddles are 1 and -i — no multiplies.
__device__ __forceinline__ void dif_last2(cpx* c, int tid) {
    int i0 = 4 * tid;
    int ia = A(i0), ib = A(i0 + 1), ic = A(i0 + 2), id = A(i0 + 3);
    cpx a = c[ia], b = c[ib], cc = c[ic], d = c[id];
    cpx a1 = cadd(a, cc);
    cpx c1 = csub(a, cc);
    cpx b1 = cadd(b, d);
    cpx bd = csub(b, d);
    cpx d1 = make_float2(bd.y, -bd.x);                        // -i*(b-d)
    c[ia] = cadd(a1, b1);
    c[ib] = csub(a1, b1);
    c[ic] = cadd(c1, d1);
    c[id] = csub(c1, d1);
    __syncthreads();
}

__device__ __forceinline__ void fft1024(cpx* c, int tid, const cpx* tw) {
    dif_fused<512>(c, tid, tw[0]);
    dif_fused<128>(c, tid, tw[1]);
    dif_fused<32>(c, tid, tw[2]);
    dif_fused<8>(c, tid, tw[3]);
    dif_last2(c, tid);
}

// Conjugate pair-unpack: one (E,O,t=w*O) yields BOTH ends.
//   X[k]      = E + t
//   X[1024-k] = conj(E - t)   (E[-k]=conj E, O[-k]=conj O, w' = -conj w)
// Xm returned as (E - t); its .x equals Re X[1024-k] (all we ever need,
// plus |Xm|^2 = |X[1024-k]|^2 since conj preserves magnitude).
__device__ __forceinline__ void unpack_pair(const cpx* s_c, int k, cpx w,
                                            cpx& Xk, cpx& Xm) {
    int kk = k & (N1 - 1);
    int mm = (N1 - kk) & (N1 - 1);
    cpx Zk = s_c[A(brev10(kk))];
    cpx Zm = s_c[A(brev10(mm))];
    float Ex = 0.5f * (Zk.x + Zm.x), Ey = 0.5f * (Zk.y - Zm.y);
    float Ox = 0.5f * (Zk.y + Zm.y), Oy = 0.5f * (Zm.x - Zk.x);
    float tx = w.x * Ox - w.y * Oy, ty = w.x * Oy + w.y * Ox;
    Xk = make_float2(Ex + tx, Ey + ty);
    Xm = make_float2(Ex - tx, Ey - ty);
}

// NO min-waves arg (r6: (256,w) caps VGPR at 256/w -> spills for w>=5, and
// pins residency for small w). Spill canary: WRITE_SIZE must stay ~32.3 MB.
__global__ __launch_bounds__(256)
void cheaptrick_kernel(const float* __restrict__ x,
                       const float* __restrict__ f0in,
                       float* __restrict__ out) {
    __shared__ cpx   s_c[1088];
    __shared__ float s_P[1026];
    __shared__ float s_scan[16];
    // s_C aliases s_c: scan writes after FFT1 data is dead (P extracted,
    // barrier between), s_C dead before FFT2 pack overwrites (barrier
    // between). Pattern validated in r8. Needs 1097 floats < 8704 B.
    float* s_C = (float*)s_c;

    const int tid  = threadIdx.x;
    const int lane = tid & 63;
    const int wid  = tid >> 6;
    const int n    = blockIdx.x;
    const int b    = blockIdx.y;

    float f0 = f0in[b * NFRAMES + n];
    const float F_MIN = 72000.0f / 2045.0f;
    if (f0 <= F_MIN) f0 = 500.0f;

    // ---- frame extraction + raw window (thread-contiguous l = 8t+j) ----
    float fr[8], wn[8];
    float hwl = rintf(36000.0f / f0);
    float s_w2 = 0.0f, s_w = 0.0f, s_fw = 0.0f;
    int base_idx = n * FPER - N1 + 8 * tid;
#pragma unroll
    for (int j = 0; j < 8; ++j) {
        int l = 8 * tid + j;
        float relf = (float)(l - N1);
        int idx = max(0, min(TLEN - 1, base_idx + j));
        fr[j] = x[b * TLEN + idx];
        float w = 0.0f;
        if (fabsf(relf) <= hwl) {
            w = 0.5f * __cosf(PIF * relf / 36000.0f * f0) + 0.5f;
        }
        wn[j] = w;
        s_w2 += w * w;
        s_w  += w;
        s_fw += fr[j] * w;
    }
#pragma unroll
    for (int off = 32; off > 0; off >>= 1) {
        s_w2 += __shfl_down(s_w2, off, 64);
        s_w  += __shfl_down(s_w,  off, 64);
        s_fw += __shfl_down(s_fw, off, 64);
    }
    if (lane == 0) {
        s_scan[wid]     = s_w2;
        s_scan[4 + wid] = s_w;
        s_scan[8 + wid] = s_fw;
    }
    __syncthreads();
    float w2sum = s_scan[0] + s_scan[1] + s_scan[2] + s_scan[3];
    float wsum  = s_scan[4] + s_scan[5] + s_scan[6] + s_scan[7];
    float fwsum = s_scan[8] + s_scan[9] + s_scan[10] + s_scan[11];
    float wscale = 1.0f / sqrtf(w2sum);
    float dc = fwsum / wsum;
    __syncthreads();          // s_scan reuse below

    // ---- FFT1 pack (register-local): z[m] = w[2m] + i*w[2m+1] ----
#pragma unroll
    for (int j = 0; j < 4; ++j) {
        float v0 = wscale * wn[2 * j]     * (fr[2 * j]     - dc);
        float v1 = wscale * wn[2 * j + 1] * (fr[2 * j + 1] - dc);
        s_c[A(4 * tid + j)] = make_float2(v0, v1);
    }

    // ---- twiddle caches (fr/wn now dead; computed once, reused by 3 FFTs) ----
    cpx tw[4], u2048;
    {
        float sn, cs;
        __sincosf(-PIF * (float)(tid & 255) * (1.0f / 512.0f), &sn, &cs);
        tw[0] = make_float2(cs, sn);
        __sincosf(-PIF * (float)(tid & 63) * (1.0f / 128.0f), &sn, &cs);
        tw[1] = make_float2(cs, sn);
        __sincosf(-PIF * (float)(tid & 15) * (1.0f / 32.0f), &sn, &cs);
        tw[2] = make_float2(cs, sn);
        __sincosf(-PIF * (float)(tid & 3) * (1.0f / 8.0f), &sn, &cs);
        tw[3] = make_float2(cs, sn);
        __sincosf(-PIF * (float)tid * (1.0f / 1024.0f), &sn, &cs);
        u2048 = make_float2(cs, sn);          // W_2048^tid
    }
    const float RH = 0.70710678118654752f;
    // W_2048^(tid+256) = u2048 * e^{-i pi/4}
    const cpx u2048b = cmul(u2048, make_float2(RH, -RH));
    const cpx wmid   = make_float2(0.0f, -1.0f);   // W_2048^512

    __syncthreads();
    fft1024(s_c, tid, tw);

    // ---- pair-unpack + power spectrum: k in [0,511] covers [513,1024] too ----
#pragma unroll
    for (int c2 = 0; c2 < 2; ++c2) {
        int k = tid + (c2 << 8);
        cpx Xk, Xm;
        unpack_pair(s_c, k, (c2 == 0) ? u2048 : u2048b, Xk, Xm);
        s_P[k]        = Xk.x * Xk.x + Xk.y * Xk.y;
        s_P[1024 - k] = Xm.x * Xm.x + Xm.y * Xm.y;
    }
    if (tid == 0) {
        cpx Xk, Xm;
        unpack_pair(s_c, 512, wmid, Xk, Xm);
        s_P[512] = Xk.x * Xk.x + Xk.y * Xk.y;
    }
    __syncthreads();

    // ---- sub-f0 replacement ----
    float rate = f0 * (2048.0f / 24000.0f);
    int kmax = (int)floorf(rate);
    float repl = 0.0f;
    if (tid <= kmax) {
        float m = rate - (float)tid;
        int lo = (int)floorf(m);
        lo = max(0, min(K1 - 2, lo));
        float frac = m - (float)lo;
        repl = s_P[lo] * (1.0f - frac) + s_P[lo + 1] * frac;
    }
    __syncthreads();
    if (tid <= kmax) s_P[tid] += repl;
    __syncthreads();

    // ---- reflected cumsum: serial-5 + wave shuffle scan -> s_C (alias s_c) ----
    float loc[5];
    float run = 0.0f;
    int basej = tid * 5;
#pragma unroll
    for (int c = 0; c < 5; ++c) {
        int j = basej + c;
        float v = 0.0f;
        if (j < MTOT) {
            int a = abs(j - KPAD);
            if (a > N1) a = NFFT - a;
            v = s_P[a] * (24000.0f / 2048.0f);
        }
        run += v;
        loc[c] = run;
    }
    float v = run;
#pragma unroll
    for (int off = 1; off < 64; off <<= 1) {
        float o = __shfl_up(v, off, 64);
        if (lane >= off) v += o;
    }
    if (lane == 63) s_scan[wid] = v;
    __syncthreads();
    float wbase = 0.0f;
#pragma unroll
    for (int w = 0; w < 4; ++w) wbase += (w < wid) ? s_scan[w] : 0.0f;
    float prefix = wbase + v - run;
#pragma unroll
    for (int c = 0; c < 5; ++c) {
        int j = basej + c;
        if (j < MTOT) s_C[j] = prefix + loc[c];
    }
    __syncthreads();

    // ---- rectangular smoothing + log ----
    float width = f0 * (2.0f / 3.0f);
    float wbins = width * (2048.0f / 24000.0f);
#pragma unroll
    for (int c5 = 0; c5 < 5; ++c5) {
        int k = tid + (c5 << 8);
        if (k < K1) {
            float pos_lo = (float)k - 0.5f * wbins + ((float)KPAD - 0.5f);
            float pos_hi = pos_lo + wbins;
            int llo = (int)floorf(pos_lo); llo = max(0, min(MTOT - 2, llo));
            float flo = pos_lo - (float)llo;
            float clo = s_C[llo] + (s_C[llo + 1] - s_C[llo]) * flo;
            int lhi = (int)floorf(pos_hi); lhi = max(0, min(MTOT - 2, lhi));
            float fhi = pos_hi - (float)lhi;
            float chi = s_C[lhi] + (s_C[lhi + 1] - s_C[lhi]) * fhi;
            s_P[k] = __logf((chi - clo) / width);
        }
    }
    __syncthreads();

    // ---- FFT2: pack even extension of logP (overwrites s_C alias — safe) ----
#pragma unroll
    for (int c = 0; c < 4; ++c) {
        int m = tid + (c << 8);
        int j0 = 2 * m;
        int j1 = 2 * m + 1;
        float v0 = (j0 <= N1) ? s_P[j0] : s_P[NFFT - j0];
        float v1 = (j1 <= N1) ? s_P[j1] : s_P[NFFT - j1];
        s_c[A(m)] = make_float2(v0, v1);
    }
    __syncthreads();
    fft1024(s_c, tid, tw);

    // ---- pair-unpack + lifter -> s_P ; cl via cos(2a)=1-2sin^2(a) ----
#pragma unroll
    for (int c2 = 0; c2 < 2; ++c2) {
        int k = tid + (c2 << 8);
        cpx Xk, Xm;
        unpack_pair(s_c, k, (c2 == 0) ? u2048 : u2048b, Xk, Xm);
        {
            float cep = Xk.x * (1.0f / 2048.0f);
            float pz = PIF * f0 * ((float)k * (1.0f / 24000.0f));
            float s = __sinf(pz);
            float sl = (k != 0) ? (s / pz) : 1.0f;
            s_P[k] = cep * sl * (1.0f + 0.6f * s * s);
        }
        {
            int km = 1024 - k;                 // in [513,1024], never 0
            float cep = Xm.x * (1.0f / 2048.0f);
            float pz = PIF * f0 * ((float)km * (1.0f / 24000.0f));
            float s = __sinf(pz);
            s_P[km] = cep * (s / pz) * (1.0f + 0.6f * s * s);
        }
    }
    if (tid == 0) {
        cpx Xk, Xm;
        unpack_pair(s_c, 512, wmid, Xk, Xm);
        float cep = Xk.x * (1.0f / 2048.0f);
        float pz = PIF * f0 * (512.0f / 24000.0f);
        float s = __sinf(pz);
        s_P[512] = cep * (s / pz) * (1.0f + 0.6f * s * s);
    }
    __syncthreads();

    // ---- FFT3: pack even extension of lifted cepstrum ----
#pragma unroll
    for (int c = 0; c < 4; ++c) {
        int m = tid + (c << 8);
        int j0 = 2 * m;
        int j1 = 2 * m + 1;
        float v0 = (j0 <= N1) ? s_P[j0] : s_P[NFFT - j0];
        float v1 = (j1 <= N1) ? s_P[j1] : s_P[NFFT - j1];
        s_c[A(m)] = make_float2(v0, v1);
    }
    __syncthreads();
    fft1024(s_c, tid, tw);

    // ---- pair-unpack + store ----
    float* orow = out + (size_t)(b * NFRAMES + n) * K1;
#pragma unroll
    for (int c2 = 0; c2 < 2; ++c2) {
        int k = tid + (c2 << 8);
        cpx Xk, Xm;
        unpack_pair(s_c, k, (c2 == 0) ? u2048 : u2048b, Xk, Xm);
        orow[k]        = Xk.x;
        orow[1024 - k] = Xm.x;
    }
    if (tid == 0) {
        cpx Xk, Xm;
        unpack_pair(s_c, 512, wmid, Xk, Xm);
        orow[512] = Xk.x;
    }
}

extern "C" void kernel_launch(void* const* d_in, const int* in_sizes, int n_in,
                              void* d_out, int out_size, void* d_ws, size_t ws_size,
                              hipStream_t stream) {
    (void)in_sizes; (void)n_in; (void)d_ws; (void)ws_size; (void)out_size;
    const float* x  = (const float*)d_in[0];
    const float* f0 = (const float*)d_in[1];
    float* out = (float*)d_out;
    dim3 grid(NFRAMES, BATCH);
    hipLaunchKernelGGL(cheaptrick_kernel, grid, dim3(256), 0, stream, x, f0, out);
}

// Round 10
// 141.179 us; speedup vs baseline: 1.1820x; 1.0682x over previous
//
#include <hip/hip_runtime.h>
#include <math.h>

#define NFFT   2048
#define N1     1024
#define K1     1025
#define KPAD   36
#define MTOT   1097   // K1 + 2*KPAD
#define NFRAMES 1001
#define TLEN   120000
#define BATCH  8
#define FPER   120
#define PIF 3.14159265358979323846f

// LDS swizzle for 8B (float2) elements; balanced for all radix-4 strides and
// the stride-16 brev gathers.
#define A(i) ((i) + ((i) >> 4))      // max 1023 -> 1086; array sized 1088

typedef float2 cpx;
__device__ __forceinline__ cpx cmul(cpx a, cpx b) {
    return make_float2(a.x * b.x - a.y * b.y, a.x * b.y + a.y * b.x);
}
__device__ __forceinline__ cpx cadd(cpx a, cpx b) { return make_float2(a.x + b.x, a.y + b.y); }
__device__ __forceinline__ cpx csub(cpx a, cpx b) { return make_float2(a.x - b.x, a.y - b.y); }

__device__ __forceinline__ int brev10(int v) {
    return (int)(__brev((unsigned)v) >> 22);
}

// ---- fused radix-4 DIF stage (spans H and H/2); w1 = W_{2H}^{tid&(H/2-1)} ----
template<int H>
__device__ __forceinline__ void dif_fused(cpx* c, int tid, cpx w1) {
    int r  = tid & (H / 2 - 1);
    int i0 = (tid / (H / 2)) * (2 * H) + r;
    int ia = A(i0), ib = A(i0 + H / 2), ic = A(i0 + H), id = A(i0 + 3 * H / 2);
    cpx a = c[ia], b = c[ib], cc = c[ic], d = c[id];
    cpx w1n = make_float2(w1.y, -w1.x);                       // -i*w1
    cpx w2  = make_float2(w1.x * w1.x - w1.y * w1.y, 2.0f * w1.x * w1.y);
    cpx a1 = cadd(a, cc);
    cpx c1 = cmul(csub(a, cc), w1);
    cpx b1 = cadd(b, d);
    cpx d1 = cmul(csub(b, d), w1n);
    c[ia] = cadd(a1, b1);
    c[ib] = cmul(csub(a1, b1), w2);
    c[ic] = cadd(c1, d1);
    c[id] = cmul(csub(c1, d1), w2);
    __syncthreads();
}

// last stage (H=2): twiddles are 1 and -i — no multiplies.
__device__ __forceinline__ void dif_last2(cpx* c, int tid) {
    int i0 = 4 * tid;
    int ia = A(i0), ib = A(i0 + 1), ic = A(i0 + 2), id = A(i0 + 3);
    cpx a = c[ia], b = c[ib], cc = c[ic], d = c[id];
    cpx a1 = cadd(a, cc);
    cpx c1 = csub(a, cc);
    cpx b1 = cadd(b, d);
    cpx bd = csub(b, d);
    cpx d1 = make_float2(bd.y, -bd.x);                        // -i*(b-d)
    c[ia] = cadd(a1, b1);
    c[ib] = csub(a1, b1);
    c[ic] = cadd(c1, d1);
    c[id] = csub(c1, d1);
    __syncthreads();
}

// Stage 1 (H=512) in registers: thread t owns z[m], m = t + 256c — exactly
// the H=512 butterfly group. Butterfly + direct store replaces pack-write,
// stage-1 read/write, and one barrier. w1 = W_1024^tid (= tw[0]).
__device__ __forceinline__ void stage1_store(const cpx z[4], cpx* s_c, int tid, cpx w1) {
    cpx w1n = make_float2(w1.y, -w1.x);
    cpx w2  = make_float2(w1.x * w1.x - w1.y * w1.y, 2.0f * w1.x * w1.y);
    cpx a1 = cadd(z[0], z[2]);
    cpx c1 = cmul(csub(z[0], z[2]), w1);
    cpx b1 = cadd(z[1], z[3]);
    cpx d1 = cmul(csub(z[1], z[3]), w1n);
    s_c[A(tid)]       = cadd(a1, b1);
    s_c[A(tid + 256)] = cmul(csub(a1, b1), w2);
    s_c[A(tid + 512)] = cadd(c1, d1);
    s_c[A(tid + 768)] = cmul(csub(c1, d1), w2);
}

// Remaining stages after the fused stage 1. Caller stores via stage1_store
// first; this begins with the barrier that publishes those stores.
__device__ __forceinline__ void fft1024_rest(cpx* c, int tid, const cpx* tw) {
    __syncthreads();
    dif_fused<128>(c, tid, tw[1]);
    dif_fused<32>(c, tid, tw[2]);
    dif_fused<8>(c, tid, tw[3]);
    dif_last2(c, tid);
}

// Pack even extension of s_P (length-2048 real-even, packed to 1024 cpx)
// for m = tid + 256c, fused with stage 1.
__device__ __forceinline__ void pack_even_stage1(const float* s_P, cpx* s_c,
                                                 int tid, cpx w1) {
    cpx z[4];
#pragma unroll
    for (int c = 0; c < 4; ++c) {
        int m = tid + (c << 8);
        float v0, v1;
        if (c <= 1) {                       // 2m+1 <= 1023: direct pair
            v0 = s_P[2 * m]; v1 = s_P[2 * m + 1];
        } else if (m == 512) {              // j0=1024, j1=1025 -> mirror 1023
            v0 = s_P[1024]; v1 = s_P[1023];
        } else {                            // 2m >= 1026: mirrored pair
            v0 = s_P[2048 - 2 * m]; v1 = s_P[2047 - 2 * m];
        }
        z[c] = make_float2(v0, v1);
    }
    stage1_store(z, s_c, tid, w1);
}

// Conjugate pair-unpack: one (E,O,t=w*O) yields BOTH ends.
//   X[k] = E + t ;  X[1024-k] = conj(E - t)
__device__ __forceinline__ void unpack_pair(const cpx* s_c, int k, cpx w,
                                            cpx& Xk, cpx& Xm) {
    int kk = k & (N1 - 1);
    int mm = (N1 - kk) & (N1 - 1);
    cpx Zk = s_c[A(brev10(kk))];
    cpx Zm = s_c[A(brev10(mm))];
    float Ex = 0.5f * (Zk.x + Zm.x), Ey = 0.5f * (Zk.y - Zm.y);
    float Ox = 0.5f * (Zk.y + Zm.y), Oy = 0.5f * (Zm.x - Zk.x);
    float tx = w.x * Ox - w.y * Oy, ty = w.x * Oy + w.y * Ox;
    Xk = make_float2(Ex + tx, Ey + ty);
    Xm = make_float2(Ex - tx, Ey - ty);
}

// NO min-waves arg (r6: (256,w) caps VGPR at 256/w -> spills for w>=5, and
// pins residency for small w). Spill canary: WRITE_SIZE must stay ~32.3 MB.
__global__ __launch_bounds__(256)
void cheaptrick_kernel(const float* __restrict__ x,
                       const float* __restrict__ f0in,
                       float* __restrict__ out) {
    __shared__ cpx   s_c[1088];
    __shared__ float s_P[1026];
    __shared__ float s_scan[16];
    // s_C aliases s_c (lifetime-disjoint, barrier-separated; validated r8/r9).
    float* s_C = (float*)s_c;

    const int tid  = threadIdx.x;
    const int lane = tid & 63;
    const int wid  = tid >> 6;
    const int n    = blockIdx.x;
    const int b    = blockIdx.y;

    float f0 = f0in[b * NFRAMES + n];
    const float F_MIN = 72000.0f / 2045.0f;
    if (f0 <= F_MIN) f0 = 500.0f;

    // ---- frame extraction + raw window, stage-1-friendly mapping ----
    // pair c holds samples l = 2*tid + 512c + {0,1}  (z[m], m = tid + 256c).
    // Wave-level: 64 lanes x 8B contiguous per (c,e) chunk — coalesced.
    float fr[8], wn[8];
    float hwl = rintf(36000.0f / f0);
    float s_w2 = 0.0f, s_w = 0.0f, s_fw = 0.0f;
    const float* xrow = x + (size_t)b * TLEN;
    int base_idx = n * FPER - N1;
#pragma unroll
    for (int c = 0; c < 4; ++c) {
#pragma unroll
        for (int e = 0; e < 2; ++e) {
            int l = 2 * tid + (c << 9) + e;
            float relf = (float)(l - N1);
            int idx = max(0, min(TLEN - 1, base_idx + l));
            float v = xrow[idx];
            float w = 0.0f;
            if (fabsf(relf) <= hwl) {
                w = 0.5f * __cosf(PIF * relf / 36000.0f * f0) + 0.5f;
            }
            fr[2 * c + e] = v;
            wn[2 * c + e] = w;
            s_w2 += w * w;
            s_w  += w;
            s_fw += v * w;
        }
    }
#pragma unroll
    for (int off = 32; off > 0; off >>= 1) {
        s_w2 += __shfl_down(s_w2, off, 64);
        s_w  += __shfl_down(s_w,  off, 64);
        s_fw += __shfl_down(s_fw, off, 64);
    }
    if (lane == 0) {
        s_scan[wid]     = s_w2;
        s_scan[4 + wid] = s_w;
        s_scan[8 + wid] = s_fw;
    }
    __syncthreads();
    float w2sum = s_scan[0] + s_scan[1] + s_scan[2] + s_scan[3];
    float wsum  = s_scan[4] + s_scan[5] + s_scan[6] + s_scan[7];
    float fwsum = s_scan[8] + s_scan[9] + s_scan[10] + s_scan[11];
    float wscale = 1.0f / sqrtf(w2sum);
    float dc = fwsum / wsum;
    __syncthreads();          // s_scan reuse below

    // ---- tw[0] first (needed by fused stage 1 while fr/wn still live) ----
    cpx tw[4];
    {
        float sn, cs;
        __sincosf(-PIF * (float)tid * (1.0f / 512.0f), &sn, &cs);
        tw[0] = make_float2(cs, sn);      // W_1024^tid
    }

    // ---- FFT1: pack (register-local) fused with stage 1 ----
    {
        cpx z[4];
#pragma unroll
        for (int c = 0; c < 4; ++c) {
            float v0 = wscale * wn[2 * c]     * (fr[2 * c]     - dc);
            float v1 = wscale * wn[2 * c + 1] * (fr[2 * c + 1] - dc);
            z[c] = make_float2(v0, v1);
        }
        stage1_store(z, s_c, tid, tw[0]);
    }

    // ---- remaining twiddles (fr/wn dead now) ----
    cpx u2048;
    {
        float sn, cs;
        __sincosf(-PIF * (float)(tid & 63) * (1.0f / 128.0f), &sn, &cs);
        tw[1] = make_float2(cs, sn);
        __sincosf(-PIF * (float)(tid & 15) * (1.0f / 32.0f), &sn, &cs);
        tw[2] = make_float2(cs, sn);
        __sincosf(-PIF * (float)(tid & 3) * (1.0f / 8.0f), &sn, &cs);
        tw[3] = make_float2(cs, sn);
        __sincosf(-PIF * (float)tid * (1.0f / 1024.0f), &sn, &cs);
        u2048 = make_float2(cs, sn);      // W_2048^tid
    }
    const float RH = 0.70710678118654752f;
    const cpx u2048b = cmul(u2048, make_float2(RH, -RH));  // W_2048^(tid+256)
    const cpx wmid   = make_float2(0.0f, -1.0f);           // W_2048^512

    fft1024_rest(s_c, tid, tw);

    // ---- pair-unpack + power spectrum ----
#pragma unroll
    for (int c2 = 0; c2 < 2; ++c2) {
        int k = tid + (c2 << 8);
        cpx Xk, Xm;
        unpack_pair(s_c, k, (c2 == 0) ? u2048 : u2048b, Xk, Xm);
        s_P[k]        = Xk.x * Xk.x + Xk.y * Xk.y;
        s_P[1024 - k] = Xm.x * Xm.x + Xm.y * Xm.y;
    }
    if (tid == 0) {
        cpx Xk, Xm;
        unpack_pair(s_c, 512, wmid, Xk, Xm);
        s_P[512] = Xk.x * Xk.x + Xk.y * Xk.y;
    }
    __syncthreads();

    // ---- sub-f0 replacement ----
    float rate = f0 * (2048.0f / 24000.0f);
    int kmax = (int)floorf(rate);
    float repl = 0.0f;
    if (tid <= kmax) {
        float m = rate - (float)tid;
        int lo = (int)floorf(m);
        lo = max(0, min(K1 - 2, lo));
        float frac = m - (float)lo;
        repl = s_P[lo] * (1.0f - frac) + s_P[lo + 1] * frac;
    }
    __syncthreads();
    if (tid <= kmax) s_P[tid] += repl;
    __syncthreads();

    // ---- reflected cumsum: serial-5 + wave shuffle scan -> s_C (alias s_c) ----
    float loc[5];
    float run = 0.0f;
    int basej = tid * 5;
#pragma unroll
    for (int c = 0; c < 5; ++c) {
        int j = basej + c;
        float v = 0.0f;
        if (j < MTOT) {
            int a = abs(j - KPAD);
            if (a > N1) a = NFFT - a;
            v = s_P[a] * (24000.0f / 2048.0f);
        }
        run += v;
        loc[c] = run;
    }
    float v = run;
#pragma unroll
    for (int off = 1; off < 64; off <<= 1) {
        float o = __shfl_up(v, off, 64);
        if (lane >= off) v += o;
    }
    if (lane == 63) s_scan[wid] = v;
    __syncthreads();
    float wbase = 0.0f;
#pragma unroll
    for (int w = 0; w < 4; ++w) wbase += (w < wid) ? s_scan[w] : 0.0f;
    float prefix = wbase + v - run;
#pragma unroll
    for (int c = 0; c < 5; ++c) {
        int j = basej + c;
        if (j < MTOT) s_C[j] = prefix + loc[c];
    }
    __syncthreads();

    // ---- rectangular smoothing + log ----
    float width = f0 * (2.0f / 3.0f);
    float wbins = width * (2048.0f / 24000.0f);
#pragma unroll
    for (int c5 = 0; c5 < 5; ++c5) {
        int k = tid + (c5 << 8);
        if (k < K1) {
            float pos_lo = (float)k - 0.5f * wbins + ((float)KPAD - 0.5f);
            float pos_hi = pos_lo + wbins;
            int llo = (int)floorf(pos_lo); llo = max(0, min(MTOT - 2, llo));
            float flo = pos_lo - (float)llo;
            float clo = s_C[llo] + (s_C[llo + 1] - s_C[llo]) * flo;
            int lhi = (int)floorf(pos_hi); lhi = max(0, min(MTOT - 2, lhi));
            float fhi = pos_hi - (float)lhi;
            float chi = s_C[lhi] + (s_C[lhi + 1] - s_C[lhi]) * fhi;
            s_P[k] = __logf((chi - clo) / width);
        }
    }
    __syncthreads();

    // ---- FFT2: pack even extension of logP fused with stage 1 ----
    pack_even_stage1(s_P, s_c, tid, tw[0]);
    fft1024_rest(s_c, tid, tw);

    // ---- pair-unpack + lifter -> s_P ; cl via cos(2a)=1-2sin^2(a) ----
#pragma unroll
    for (int c2 = 0; c2 < 2; ++c2) {
        int k = tid + (c2 << 8);
        cpx Xk, Xm;
        unpack_pair(s_c, k, (c2 == 0) ? u2048 : u2048b, Xk, Xm);
        {
            float cep = Xk.x * (1.0f / 2048.0f);
            float pz = PIF * f0 * ((float)k * (1.0f / 24000.0f));
            float s = __sinf(pz);
            float sl = (k != 0) ? (s / pz) : 1.0f;
            s_P[k] = cep * sl * (1.0f + 0.6f * s * s);
        }
        {
            int km = 1024 - k;                 // in [513,1024], never 0
            float cep = Xm.x * (1.0f / 2048.0f);
            float pz = PIF * f0 * ((float)km * (1.0f / 24000.0f));
            float s = __sinf(pz);
            s_P[km] = cep * (s / pz) * (1.0f + 0.6f * s * s);
        }
    }
    if (tid == 0) {
        cpx Xk, Xm;
        unpack_pair(s_c, 512, wmid, Xk, Xm);
        float cep = Xk.x * (1.0f / 2048.0f);
        float pz = PIF * f0 * (512.0f / 24000.0f);
        float s = __sinf(pz);
        s_P[512] = cep * (s / pz) * (1.0f + 0.6f * s * s);
    }
    __syncthreads();

    // ---- FFT3: pack even extension of lifted cepstrum fused with stage 1 ----
    pack_even_stage1(s_P, s_c, tid, tw[0]);
    fft1024_rest(s_c, tid, tw);

    // ---- pair-unpack + store ----
    float* orow = out + (size_t)(b * NFRAMES + n) * K1;
#pragma unroll
    for (int c2 = 0; c2 < 2; ++c2) {
        int k = tid + (c2 << 8);
        cpx Xk, Xm;
        unpack_pair(s_c, k, (c2 == 0) ? u2048 : u2048b, Xk, Xm);
        orow[k]        = Xk.x;
        orow[1024 - k] = Xm.x;
    }
    if (tid == 0) {
        cpx Xk, Xm;
        unpack_pair(s_c, 512, wmid, Xk, Xm);
        orow[512] = Xk.x;
    }
}

extern "C" void kernel_launch(void* const* d_in, const int* in_sizes, int n_in,
                              void* d_out, int out_size, void* d_ws, size_t ws_size,
                              hipStream_t stream) {
    (void)in_sizes; (void)n_in; (void)d_ws; (void)ws_size; (void)out_size;
    const float* x  = (const float*)d_in[0];
    const float* f0 = (const float*)d_in[1];
    float* out = (float*)d_out;
    dim3 grid(NFRAMES, BATCH);
    hipLaunchKernelGGL(cheaptrick_kernel, grid, dim3(256), 0, stream, x, f0, out);
}